// Round 2
// baseline (294.885 us; speedup 1.0000x reference)
//
#include <hip/hip_runtime.h>
#include <hip/hip_bf16.h>

#define NB 128        // batch B
#define NMEM 100000   // N
#define ND 128        // D
constexpr float T_INV = 1.0f / 0.07f;
constexpr float K2 = 20.6099442241331655f;   // log2(e)/T  (T=0.07)

constexpr int LROW = ND + 8;              // xs LDS row: 136 bf16 = 272 B
constexpr int NTW = NMEM / 16;            // 6250 wave-tiles of 16 n-rows (exact)
constexpr int GRID = 1024;                // fill 3-4 blocks/CU residency
constexpr int NWAVES = GRID * 4;          // 4096
constexpr int ZSTRIDE = 16;               // zbuf slots 64 B apart

typedef __attribute__((ext_vector_type(8))) __bf16 bf16x8;
typedef __attribute__((ext_vector_type(4))) float f32x4;
struct bf4 { __bf16 a, b, c, d; };

// A-frag: A[m=lane&15][k=(lane>>4)*8+j]; B-frag: B[n=lane&15][k=(lane>>4)*8+j]
// C/D: col(n)=lane&15, row(m)=(lane>>4)*4+reg   [HW-verified m89/m91]
// launch_bounds(256,3): VGPR cap 168 -> >=3 blocks/CU (12 waves/CU); LDS 35.8KB*3=107KB OK
template<bool PASS2>
__global__ __launch_bounds__(256, 3) void nce_wave(
    const float* __restrict__ x,
    const int* __restrict__ labels,
    const float* __restrict__ mem_da,
    float* __restrict__ zbuf,
    float* __restrict__ out,
    float* __restrict__ maskout)
{
  __shared__ __bf16 xs[NB * LROW];   // 34816 B
  __shared__ float aux[NB];          // pass1: lbl_b; pass2: -log2(Z)
  __shared__ float zl[NB];           // pass1 block Z partials

  const int tid = threadIdx.x;

  // ---- one-time stage: x -> bf16 LDS (4 chunks of 4 float4 to cap VGPR spike) ----
  const float4* x4 = (const float4*)x;
  #pragma unroll
  for (int c = 0; c < 4; ++c) {
    float4 xv[4];
    #pragma unroll
    for (int i = 0; i < 4; ++i) xv[i] = x4[tid + (c * 4 + i) * 256];
    #pragma unroll
    for (int i = 0; i < 4; ++i) {
      int g4 = tid + (c * 4 + i) * 256;
      *(bf4*)&xs[(g4 >> 5) * LROW + (g4 & 31) * 4] =
          bf4{(__bf16)xv[i].x, (__bf16)xv[i].y, (__bf16)xv[i].z, (__bf16)xv[i].w};
    }
  }
  if (tid < NB) {
    if (PASS2) aux[tid] = -__log2f(zbuf[tid * ZSTRIDE]);
    else { aux[tid] = (float)labels[tid]; zl[tid] = 0.f; }
  }
  __syncthreads();                   // the ONLY barrier before the wave loop

  const int wid = tid >> 6, lane = tid & 63, q = lane >> 4, l16 = lane & 15;
  const int wgid = blockIdx.x * 4 + wid;

  f32x4 zacc[8];
  #pragma unroll
  for (int mt = 0; mt < 8; ++mt) zacc[mt] = (f32x4){0.f, 0.f, 0.f, 0.f};

  // ---- barrier-free wave loop: tiles wgid, wgid+4096, ... (1-2 tiles/wave) ----
  for (int t = wgid; t < NTW; t += NWAVES) {
    const float* rowp = mem_da + (size_t)(t * 16 + l16) * 129;   // lane's n-row
    float ln;
    if (!PASS2) ln = rowp[0];                                     // bank label
    // B fragments: 8 feature floats per kc, direct global -> regs
    float bf[4][8];
    #pragma unroll
    for (int kc = 0; kc < 4; ++kc)
      __builtin_memcpy(&bf[kc][0], rowp + 1 + kc * 32 + q * 8, 32);
    bf16x8 bb[4];
    #pragma unroll
    for (int kc = 0; kc < 4; ++kc)
      #pragma unroll
      for (int j = 0; j < 8; ++j) bb[kc][j] = (__bf16)bf[kc][j];

    f32x4 acc[8];
    #pragma unroll
    for (int mt = 0; mt < 8; ++mt) acc[mt] = (f32x4){0.f, 0.f, 0.f, 0.f};
    #pragma unroll
    for (int kc = 0; kc < 4; ++kc) {
      const int ko = kc * 32 + q * 8;
      #pragma unroll
      for (int mt = 0; mt < 8; ++mt) {
        bf16x8 a = *(const bf16x8*)&xs[(mt * 16 + l16) * LROW + ko];
        acc[mt] = __builtin_amdgcn_mfma_f32_16x16x32_bf16(a, bb[kc], acc[mt], 0, 0, 0);
      }
    }

    const size_t n = (size_t)t * 16 + l16;
    #pragma unroll
    for (int mt = 0; mt < 8; ++mt) {
      // per-m constant: label (pass1) or -log2(Z) (pass2); 16-lane broadcast read
      f32x4 amv = *(const f32x4*)&aux[mt * 16 + q * 4];
      #pragma unroll
      for (int r = 0; r < 4; ++r) {
        const size_t off = (size_t)(mt * 16 + q * 4 + r) * NMEM + n;
        if (!PASS2) {
          zacc[mt][r] += exp2f(acc[mt][r] * K2);
          maskout[off] = (ln == amv[r]) ? 1.0f : 0.0f;
        } else {
          out[off] = exp2f(__builtin_fmaf(acc[mt][r], K2, amv[r]));
        }
      }
    }
  }

  // ---- pass1 finalize: butterfly within 16-lane groups -> LDS -> global ----
  if (!PASS2) {
    #pragma unroll
    for (int mt = 0; mt < 8; ++mt) {
      #pragma unroll
      for (int r = 0; r < 4; ++r) {
        float v = zacc[mt][r];
        v += __shfl_xor(v, 1);
        v += __shfl_xor(v, 2);
        v += __shfl_xor(v, 4);
        v += __shfl_xor(v, 8);
        if (l16 == 0) atomicAdd(&zl[mt * 16 + q * 4 + r], v);
      }
    }
    __syncthreads();
    if (tid < NB) atomicAdd(&zbuf[tid * ZSTRIDE], zl[tid]);
  }
}

extern "C" void kernel_launch(void* const* d_in, const int* in_sizes, int n_in,
                              void* d_out, int out_size, void* d_ws, size_t ws_size,
                              hipStream_t stream) {
  const float* x      = (const float*)d_in[0];
  const int* labels   = (const int*)d_in[2];
  const float* mem_da = (const float*)d_in[3];
  float* out     = (float*)d_out;
  float* maskout = out + (size_t)NB * NMEM;
  float* zbuf    = (float*)d_ws;     // 128*16 floats = 8192 B

  hipMemsetAsync(zbuf, 0, NB * ZSTRIDE * sizeof(float), stream);
  nce_wave<false><<<GRID, 256, 0, stream>>>(x, labels, mem_da, zbuf, nullptr, maskout);
  nce_wave<true ><<<GRID, 256, 0, stream>>>(x, labels, mem_da, zbuf, out, nullptr);
}

// Round 3
// 279.297 us; speedup vs baseline: 1.0558x; 1.0558x over previous
//
#include <hip/hip_runtime.h>
#include <hip/hip_bf16.h>

#define NB 128        // batch B
#define NMEM 100000   // N
#define ND 128        // D
constexpr float K2 = 20.6099442241331655f;   // log2(e)/T  (T=0.07)

constexpr int LROW = ND + 8;              // xs LDS row: 136 bf16 = 272 B
constexpr int NTP = NMEM / 32;            // 3125 pair-tiles of 32 n-cols (exact)
constexpr int GRID = 512;                 // 2 blocks/CU (round-0 value; (256,3) regressed)
constexpr int NWAVES = GRID * 4;          // 2048
constexpr int ZSTRIDE = 16;               // zbuf slots 64 B apart

typedef __attribute__((ext_vector_type(8))) __bf16 bf16x8;
typedef __attribute__((ext_vector_type(4))) float f32x4;
struct bf4 { __bf16 a, b, c, d; };

// SWAPPED operands vs round 0: A = mem rows (n), B = x rows (b).
// A-frag: A[n=lane&15][k=q*8+j]; B-frag: B[b=lane&15][k=q*8+j]
// C/D: col(b)=lane&15, row(n)=q*4+r   [HW-verified m89/m91]
// => each lane holds 4 CONSECUTIVE n per fragment -> f32x4 stores; a pair of
//    adjacent 16-col tiles per wave writes full 128 B output lines
//    (output row stride 400000 B = 3125*128, line-aligned).
template<bool PASS2>
__global__ __launch_bounds__(256, 2) void nce_wave(
    const float* __restrict__ x,
    const int* __restrict__ labels,
    const float* __restrict__ mem_da,
    float* __restrict__ zbuf,
    float* __restrict__ out,
    float* __restrict__ maskout)
{
  __shared__ __bf16 xs[NB * LROW];   // 34816 B
  __shared__ float aux[NB];          // pass1: lbl_b; pass2: -log2(Z_b)
  __shared__ float zl[NB];           // pass1 block Z partials

  const int tid = threadIdx.x;

  // ---- one-time stage: x -> bf16 LDS (round-0 single-shot form) ----
  const float4* x4 = (const float4*)x;
  float4 xv[16];
  #pragma unroll
  for (int i = 0; i < 16; ++i) xv[i] = x4[tid + i * 256];
  #pragma unroll
  for (int i = 0; i < 16; ++i) {
    int g4 = tid + i * 256;
    *(bf4*)&xs[(g4 >> 5) * LROW + (g4 & 31) * 4] =
        bf4{(__bf16)xv[i].x, (__bf16)xv[i].y, (__bf16)xv[i].z, (__bf16)xv[i].w};
  }
  if (tid < NB) {
    if (PASS2) aux[tid] = -__log2f(zbuf[tid * ZSTRIDE]);
    else { aux[tid] = (float)labels[tid]; zl[tid] = 0.f; }
  }
  __syncthreads();                   // the ONLY barrier before the wave loop

  const int wid = tid >> 6, lane = tid & 63, q = lane >> 4, l16 = lane & 15;
  const int wgid = blockIdx.x * 4 + wid;

  // per-lane b-row constants, hoisted: b = mt*16 + l16
  float lblb[8];
  #pragma unroll
  for (int mt = 0; mt < 8; ++mt) lblb[mt] = aux[mt * 16 + l16];

  float zacc[8];
  #pragma unroll
  for (int mt = 0; mt < 8; ++mt) zacc[mt] = 0.f;

  // ---- barrier-free wave loop over 32-col pair-tiles ----
  for (int t = wgid; t < NTP; t += NWAVES) {
    #pragma unroll
    for (int h = 0; h < 2; ++h) {
      const int n0 = t * 32 + h * 16;
      const float* rowp = mem_da + (size_t)(n0 + l16) * 129;   // lane's n-row
      float ln;
      if (!PASS2) ln = rowp[0];                                 // bank label

      // A fragments: mem row features, 32 B per kc, global -> regs
      bf16x8 ab[4];
      #pragma unroll
      for (int kc = 0; kc < 4; ++kc) {
        float tmp[8];
        __builtin_memcpy(tmp, rowp + 1 + kc * 32 + q * 8, 32);
        #pragma unroll
        for (int j = 0; j < 8; ++j) ab[kc][j] = (__bf16)tmp[j];
      }

      f32x4 acc[8];
      #pragma unroll
      for (int mt = 0; mt < 8; ++mt) acc[mt] = (f32x4){0.f, 0.f, 0.f, 0.f};
      #pragma unroll
      for (int kc = 0; kc < 4; ++kc) {
        const int ko = kc * 32 + q * 8;
        #pragma unroll
        for (int mt = 0; mt < 8; ++mt) {
          bf16x8 xb = *(const bf16x8*)&xs[(mt * 16 + l16) * LROW + ko];
          acc[mt] = __builtin_amdgcn_mfma_f32_16x16x32_bf16(ab[kc], xb, acc[mt], 0, 0, 0);
        }
      }

      // labels of the 16 n-rows live in lanes 0..15 of each 16-group
      float ml[4];
      if (!PASS2) {
        #pragma unroll
        for (int r = 0; r < 4; ++r) ml[r] = __shfl(ln, q * 4 + r, 16);
      }

      #pragma unroll
      for (int mt = 0; mt < 8; ++mt) {
        const size_t off = (size_t)(mt * 16 + l16) * NMEM + n0 + q * 4;
        if (!PASS2) {
          f32x4 mk;
          float zs = 0.f;
          #pragma unroll
          for (int r = 0; r < 4; ++r) {
            zs += exp2f(acc[mt][r] * K2);
            mk[r] = (ml[r] == lblb[mt]) ? 1.0f : 0.0f;
          }
          zacc[mt] += zs;
          *(f32x4*)&maskout[off] = mk;
        } else {
          f32x4 ov;
          #pragma unroll
          for (int r = 0; r < 4; ++r)
            ov[r] = exp2f(__builtin_fmaf(acc[mt][r], K2, lblb[mt]));
          *(f32x4*)&out[off] = ov;
        }
      }
    }
  }

  // ---- pass1 finalize: reduce over q-lanes (xor 16, 32) -> LDS -> global ----
  if (!PASS2) {
    #pragma unroll
    for (int mt = 0; mt < 8; ++mt) {
      float v = zacc[mt];
      v += __shfl_xor(v, 16);
      v += __shfl_xor(v, 32);
      if (lane < 16) atomicAdd(&zl[mt * 16 + lane], v);
    }
    __syncthreads();
    if (tid < NB) atomicAdd(&zbuf[tid * ZSTRIDE], zl[tid]);
  }
}

extern "C" void kernel_launch(void* const* d_in, const int* in_sizes, int n_in,
                              void* d_out, int out_size, void* d_ws, size_t ws_size,
                              hipStream_t stream) {
  const float* x      = (const float*)d_in[0];
  const int* labels   = (const int*)d_in[2];
  const float* mem_da = (const float*)d_in[3];
  float* out     = (float*)d_out;
  float* maskout = out + (size_t)NB * NMEM;
  float* zbuf    = (float*)d_ws;     // 128*16 floats = 8192 B

  hipMemsetAsync(zbuf, 0, NB * ZSTRIDE * sizeof(float), stream);
  nce_wave<false><<<GRID, 256, 0, stream>>>(x, labels, mem_da, zbuf, nullptr, maskout);
  nce_wave<true ><<<GRID, 256, 0, stream>>>(x, labels, mem_da, zbuf, out, nullptr);
}

// Round 4
// 216.856 us; speedup vs baseline: 1.3598x; 1.2879x over previous
//
#include <hip/hip_runtime.h>
#include <hip/hip_bf16.h>

#define NB 128        // batch B
#define NMEM 100000   // N
#define ND 128        // D
constexpr float K2 = 20.6099442241331655f;   // log2(e)/T  (T=0.07)

constexpr int LROW = ND + 8;              // xs LDS row: 136 bf16 = 272 B
constexpr int NTP = NMEM / 32;            // 3125 pair-tiles of 32 n-cols (exact)
constexpr int GRID = 512;                 // 2 blocks/CU
constexpr int NWAVES = GRID * 4;          // 2048
constexpr int ZSTRIDE = 16;               // zbuf slots 64 B apart

typedef __attribute__((ext_vector_type(8))) __bf16 bf16x8;
typedef __attribute__((ext_vector_type(4))) float f32x4;
struct bf4 { __bf16 a, b, c, d; };

// A = mem rows (n), B = x rows (b).
// A-frag: A[n=lane&15][k=q*8+j]; B-frag: B[b=lane&15][k=q*8+j]
// C/D: col(b)=lane&15, row(n)=q*4+r   [HW-verified m89/m91]
// Output line discipline: each 128B out-line (32 n-cols of one b-row, line-
// aligned since NMEM*4=400000=3125*128) is written by ONE wave via two 64B
// stores issued BACK-TO-BACK (h=0 then h=1), nontemporal -> no L2 allocation,
// no half-dirty eviction churn (round-3's 2.8x WRITE amp).
template<bool PASS2>
__global__ __launch_bounds__(256, 2) void nce_wave(
    const float* __restrict__ x,
    const int* __restrict__ labels,
    const float* __restrict__ mem_da,
    float* __restrict__ zbuf,
    float* __restrict__ out,
    float* __restrict__ maskout)
{
  __shared__ __bf16 xs[NB * LROW];   // 34816 B
  __shared__ float aux[NB];          // pass1: lbl_b; pass2: -log2(Z_b)
  __shared__ float zl[NB];           // pass1 block Z partials

  const int tid = threadIdx.x;

  // ---- one-time stage: x -> bf16 LDS ----
  const float4* x4 = (const float4*)x;
  float4 xv[16];
  #pragma unroll
  for (int i = 0; i < 16; ++i) xv[i] = x4[tid + i * 256];
  #pragma unroll
  for (int i = 0; i < 16; ++i) {
    int g4 = tid + i * 256;
    *(bf4*)&xs[(g4 >> 5) * LROW + (g4 & 31) * 4] =
        bf4{(__bf16)xv[i].x, (__bf16)xv[i].y, (__bf16)xv[i].z, (__bf16)xv[i].w};
  }
  if (tid < NB) {
    if (PASS2) aux[tid] = -__log2f(zbuf[tid * ZSTRIDE]);
    else { aux[tid] = (float)labels[tid]; zl[tid] = 0.f; }
  }
  __syncthreads();                   // the ONLY barrier before the wave loop

  const int wid = tid >> 6, lane = tid & 63, q = lane >> 4, l16 = lane & 15;
  const int wgid = blockIdx.x * 4 + wid;

  // per-lane b-row constants, hoisted: b = mt*16 + l16
  float lblb[8];
  #pragma unroll
  for (int mt = 0; mt < 8; ++mt) lblb[mt] = aux[mt * 16 + l16];

  float zacc[8];
  #pragma unroll
  for (int mt = 0; mt < 8; ++mt) zacc[mt] = 0.f;

  // ---- barrier-free wave loop over 32-col pair-tiles ----
  for (int t = wgid; t < NTP; t += NWAVES) {
    f32x4 acc[2][8];                 // [half][mt] — both halves live for store burst
    float ln[2];

    #pragma unroll
    for (int h = 0; h < 2; ++h) {
      const int n0 = t * 32 + h * 16;
      const float* rowp = mem_da + (size_t)(n0 + l16) * 129;   // lane's n-row
      if (!PASS2) ln[h] = rowp[0];                              // bank label

      // A fragments: mem row features, 32 B per kc, global -> regs
      bf16x8 ab[4];
      #pragma unroll
      for (int kc = 0; kc < 4; ++kc) {
        float tmp[8];
        __builtin_memcpy(tmp, rowp + 1 + kc * 32 + q * 8, 32);
        #pragma unroll
        for (int j = 0; j < 8; ++j) ab[kc][j] = (__bf16)tmp[j];
      }

      #pragma unroll
      for (int mt = 0; mt < 8; ++mt) acc[h][mt] = (f32x4){0.f, 0.f, 0.f, 0.f};
      #pragma unroll
      for (int kc = 0; kc < 4; ++kc) {
        const int ko = kc * 32 + q * 8;
        #pragma unroll
        for (int mt = 0; mt < 8; ++mt) {
          bf16x8 xb = *(const bf16x8*)&xs[(mt * 16 + l16) * LROW + ko];
          acc[h][mt] = __builtin_amdgcn_mfma_f32_16x16x32_bf16(ab[kc], xb, acc[h][mt], 0, 0, 0);
        }
      }
    }

    // labels of the 32 n-rows live in lanes 0..15 of each 16-group
    float ml[2][4];
    if (!PASS2) {
      #pragma unroll
      for (int h = 0; h < 2; ++h)
        #pragma unroll
        for (int r = 0; r < 4; ++r) ml[h][r] = __shfl(ln[h], q * 4 + r, 16);
    }

    // ---- store burst: per row, h=0 and h=1 64B halves back-to-back, nt ----
    #pragma unroll
    for (int mt = 0; mt < 8; ++mt) {
      const size_t base = (size_t)(mt * 16 + l16) * NMEM + t * 32 + q * 4;
      if (!PASS2) {
        f32x4 mk0, mk1;
        float zs = 0.f;
        #pragma unroll
        for (int r = 0; r < 4; ++r) {
          zs += exp2f(acc[0][mt][r] * K2);
          zs += exp2f(acc[1][mt][r] * K2);
          mk0[r] = (ml[0][r] == lblb[mt]) ? 1.0f : 0.0f;
          mk1[r] = (ml[1][r] == lblb[mt]) ? 1.0f : 0.0f;
        }
        zacc[mt] += zs;
        __builtin_nontemporal_store(mk0, (f32x4*)&maskout[base]);
        __builtin_nontemporal_store(mk1, (f32x4*)&maskout[base + 16]);
      } else {
        f32x4 ov0, ov1;
        #pragma unroll
        for (int r = 0; r < 4; ++r) {
          ov0[r] = exp2f(__builtin_fmaf(acc[0][mt][r], K2, lblb[mt]));
          ov1[r] = exp2f(__builtin_fmaf(acc[1][mt][r], K2, lblb[mt]));
        }
        __builtin_nontemporal_store(ov0, (f32x4*)&out[base]);
        __builtin_nontemporal_store(ov1, (f32x4*)&out[base + 16]);
      }
    }
  }

  // ---- pass1 finalize: reduce over q-lanes (xor 16, 32) -> LDS -> global ----
  if (!PASS2) {
    #pragma unroll
    for (int mt = 0; mt < 8; ++mt) {
      float v = zacc[mt];
      v += __shfl_xor(v, 16);
      v += __shfl_xor(v, 32);
      if (lane < 16) atomicAdd(&zl[mt * 16 + lane], v);
    }
    __syncthreads();
    if (tid < NB) atomicAdd(&zbuf[tid * ZSTRIDE], zl[tid]);
  }
}

extern "C" void kernel_launch(void* const* d_in, const int* in_sizes, int n_in,
                              void* d_out, int out_size, void* d_ws, size_t ws_size,
                              hipStream_t stream) {
  const float* x      = (const float*)d_in[0];
  const int* labels   = (const int*)d_in[2];
  const float* mem_da = (const float*)d_in[3];
  float* out     = (float*)d_out;
  float* maskout = out + (size_t)NB * NMEM;
  float* zbuf    = (float*)d_ws;     // 128*16 floats = 8192 B

  hipMemsetAsync(zbuf, 0, NB * ZSTRIDE * sizeof(float), stream);
  nce_wave<false><<<GRID, 256, 0, stream>>>(x, labels, mem_da, zbuf, nullptr, maskout);
  nce_wave<true ><<<GRID, 256, 0, stream>>>(x, labels, mem_da, zbuf, out, nullptr);
}